// Round 6
// baseline (627.889 us; speedup 1.0000x reference)
//
#include <hip/hip_runtime.h>
#include <hip/hip_bf16.h>

#define D_IN 128
#define HDIM 128
#define D_E  32
#define NC   16
#define SCAN_CHUNK 2048

typedef __attribute__((ext_vector_type(8))) short short8;
typedef __attribute__((ext_vector_type(4))) float float4v;

__device__ inline short f2bs(float f) {
  __hip_bfloat16 h = (__hip_bfloat16)f;
  return *reinterpret_cast<short*>(&h);
}

__device__ inline float bs2f(short s) {
  unsigned int u = ((unsigned int)(unsigned short)s) << 16;
  float f;
  __builtin_memcpy(&f, &u, 4);
  return f;
}

// ---------------- prologue: degree, CSR ----------------

// also records each edge's arrival slot so fill_csr needs no second atomic pass
__global__ __launch_bounds__(256) void count_deg(const int* __restrict__ ei, int* __restrict__ deg,
                                                 int* __restrict__ epos, int E) {
  int e = blockIdx.x * 256 + threadIdx.x;
  if (e < E) epos[e] = atomicAdd(&deg[ei[E + e]], 1);
}

__global__ __launch_bounds__(256) void scan_blocksums(const int* __restrict__ deg, int* __restrict__ bsum, int n) {
  __shared__ int red[256];
  int t = threadIdx.x;
  int base = blockIdx.x * SCAN_CHUNK + t * 8;
  int s = 0;
#pragma unroll
  for (int j = 0; j < 8; ++j) {
    int i = base + j;
    if (i < n) s += deg[i];
  }
  red[t] = s;
  __syncthreads();
  for (int off = 128; off > 0; off >>= 1) {
    if (t < off) red[t] += red[t + off];
    __syncthreads();
  }
  if (t == 0) bsum[blockIdx.x] = red[0];
}

__global__ __launch_bounds__(256) void scan_offsets(const int* __restrict__ bsum, int* __restrict__ boff, int nb) {
  __shared__ int s[256];
  int t = threadIdx.x;
  int v = (t < nb) ? bsum[t] : 0;
  s[t] = v;
  __syncthreads();
  for (int off = 1; off < 256; off <<= 1) {
    int u = (t >= off) ? s[t - off] : 0;
    __syncthreads();
    s[t] += u;
    __syncthreads();
  }
  if (t < nb) boff[t] = (t == 0) ? 0 : s[t - 1];
}

__global__ __launch_bounds__(256) void scan_write(const int* __restrict__ deg, const int* __restrict__ boff,
                                                  int* __restrict__ rowptr, float* __restrict__ dinv, int n) {
  __shared__ int red[256];
  int t = threadIdx.x;
  int base = blockIdx.x * SCAN_CHUNK + t * 8;
  int v[8];
  int s = 0;
#pragma unroll
  for (int j = 0; j < 8; ++j) {
    int i = base + j;
    v[j] = (i < n) ? deg[i] : 0;
    s += v[j];
  }
  red[t] = s;
  __syncthreads();
  for (int off = 1; off < 256; off <<= 1) {
    int u = (t >= off) ? red[t - off] : 0;
    __syncthreads();
    red[t] += u;
    __syncthreads();
  }
  int run = red[t] - s + boff[blockIdx.x];
#pragma unroll
  for (int j = 0; j < 8; ++j) {
    int i = base + j;
    if (i < n) {
      rowptr[i] = run;
      dinv[i] = rsqrtf((float)v[j] + 1.0f);
    }
    run += v[j];
  }
}

__global__ __launch_bounds__(256) void fill_csr(const int* __restrict__ ei, const int* __restrict__ rowptr,
                                                const int* __restrict__ epos, int* __restrict__ col, int E) {
  int e = blockIdx.x * 256 + threadIdx.x;
  if (e < E) {
    int d = ei[E + e];
    col[rowptr[d] + epos[e]] = ei[e];
  }
}

// ---------------- weight repack into MFMA B-fragment order (bf16) ----------------
__global__ __launch_bounds__(256) void repack_w128(const float* __restrict__ W, short* __restrict__ wp) {
  int idx = blockIdx.x * 256 + threadIdx.x;  // 4*8*64*8 = 16384
  if (idx < 16384) {
    int j = idx & 7, lane = (idx >> 3) & 63, t = (idx >> 9) & 7, kc = idx >> 12;
    int k = kc * 32 + (lane >> 4) * 8 + j;
    int nn = t * 16 + (lane & 15);
    wp[idx] = f2bs(W[k * HDIM + nn]);
  }
}

__global__ __launch_bounds__(256) void repack_wcp(const float* __restrict__ Wfc, short* __restrict__ wp) {
  int idx = blockIdx.x * 256 + threadIdx.x;  // 4*2*64*8 = 4096
  if (idx < 4096) {
    int j = idx & 7, lane = (idx >> 3) & 63, t = (idx >> 9) & 1, kc = idx >> 10;
    int k = kc * 32 + (lane >> 4) * 8 + j;
    int nn = t * 16 + (lane & 15);
    float v = (nn < 16) ? Wfc[k * NC + nn] : Wfc[(HDIM + k) * NC + (nn - 16)];
    wp[idx] = f2bs(v);
  }
}

// Pack Wfc rows 256..287 (edge_attr block), K=32, 16 cols
__global__ __launch_bounds__(256) void repack_wea(const float* __restrict__ Wfc, short* __restrict__ wp) {
  int idx = blockIdx.x * 256 + threadIdx.x;  // 512
  if (idx < 512) {
    int j = idx & 7, lane = (idx >> 3) & 63;
    int k = (lane >> 4) * 8 + j;
    int nn = lane & 15;
    wp[idx] = f2bs(Wfc[(2 * HDIM + k) * NC + nn]);
  }
}

// ---------------- MFMA GEMM (layer 1 only): Y[n x 128] = X[n x 128] @ W, fp32 in ----------------
__global__ __launch_bounds__(256) void gemm_l1(const float* __restrict__ Xv, const short* __restrict__ wpack,
                                               __hip_bfloat16* __restrict__ Yv, const float* __restrict__ dscale, int n) {
  constexpr int NT = 8;
  __shared__ short sw[4 * NT * 512];
  int tid = threadIdx.x;
  {
    const float4* wg = (const float4*)wpack;
    float4* sg = (float4*)sw;
    for (int i = tid; i < 4 * NT * 512 / 8; i += 256) sg[i] = wg[i];
  }
  __syncthreads();
  int wave = tid >> 6, lane = tid & 63;
  int quad = lane >> 4;
  int row = blockIdx.x * 64 + wave * 16 + (lane & 15);
  bool rowok = row < n;
  float4v acc[NT];
#pragma unroll
  for (int t = 0; t < NT; ++t) acc[t] = (float4v){0.f, 0.f, 0.f, 0.f};

#pragma unroll
  for (int kc = 0; kc < 4; ++kc) {
    short8 af = {0, 0, 0, 0, 0, 0, 0, 0};
    if (rowok) {
      const float* xp = Xv + (size_t)row * 128 + kc * 32 + quad * 8;
      float4 x0 = *(const float4*)xp;
      float4 x1 = *(const float4*)(xp + 4);
      af[0] = f2bs(x0.x); af[1] = f2bs(x0.y); af[2] = f2bs(x0.z); af[3] = f2bs(x0.w);
      af[4] = f2bs(x1.x); af[5] = f2bs(x1.y); af[6] = f2bs(x1.z); af[7] = f2bs(x1.w);
    }
#pragma unroll
    for (int t = 0; t < NT; ++t) {
      short8 bfr = *(const short8*)(sw + (kc * NT + t) * 512 + lane * 8);
      acc[t] = __builtin_amdgcn_mfma_f32_16x16x32_bf16(af, bfr, acc[t], 0, 0, 0);
    }
  }
  int orow0 = blockIdx.x * 64 + wave * 16 + quad * 4;
  float dv[4];
#pragma unroll
  for (int r = 0; r < 4; ++r) dv[r] = (orow0 + r < n) ? dscale[orow0 + r] : 0.f;
#pragma unroll
  for (int t = 0; t < NT; ++t) {
    int ocol = t * 16 + (lane & 15);
#pragma unroll
    for (int r = 0; r < 4; ++r) {
      int orow = orow0 + r;
      if (orow < n) Yv[(size_t)orow * 128 + ocol] = (__hip_bfloat16)(acc[t][r] * dv[r]);
    }
  }
}

// ---------------- FUSED aggregation + GEMM ----------------
// Phase 1 (agg): each block aggregates its 64 output rows. Quad (16 lanes) owns one node,
// lane covers 8 features (16B). Batch-16 cooperative index fetch + shfl broadcast (verified
// round-4 structure). Result row (bias+relu, bf16) -> LDS tile, 16B-chunk XOR swizzle
// (chunk ^= row&7; involution, applied on write AND read -> uniform LDS banks).
// Phase 2 (MFMA): identical to gemm_mfma but A-fragments come from the LDS tile.
// Saves the 25.6MB write + 25.6MB read of the intermediate per layer.
template<int NT, bool FP32OUT, bool SCALE>
__global__ __launch_bounds__(256) void agg_gemm(const __hip_bfloat16* __restrict__ hs, const float* __restrict__ dinv,
                                                const int* __restrict__ rowptr, const int* __restrict__ deg,
                                                const int* __restrict__ col, const float* __restrict__ bias,
                                                const short* __restrict__ wpack, void* __restrict__ Yv,
                                                const float* __restrict__ dscale, int n) {
  __shared__ short sw[4 * NT * 512];
  __shared__ short st[64 * 128];  // 16 KB staged rows (swizzled)
  int tid = threadIdx.x;
  {
    const float4* wg = (const float4*)wpack;
    float4* sg = (float4*)sw;
    for (int i = tid; i < 4 * NT * 512 / 8; i += 256) sg[i] = wg[i];
  }
  int wave = tid >> 6, lane = tid & 63;
  int q = lane >> 4, ft = lane & 15;
  const short* hb = (const short*)hs;
  float4 b0 = *(const float4*)(bias + ft * 8);
  float4 b1 = *(const float4*)(bias + ft * 8 + 4);
  float bb[8] = {b0.x, b0.y, b0.z, b0.w, b1.x, b1.y, b1.z, b1.w};

  // ---- phase 1: aggregate 4 passes x 4 nodes per wave = 16 rows per wave ----
  for (int p = 0; p < 4; ++p) {
    int rl = wave * 16 + p * 4 + q;            // local row 0..63
    int i = blockIdx.x * 64 + rl;
    bool ok = i < n;
    int iS = ok ? i : (n - 1);
    int s0 = rowptr[iS];
    int dg = ok ? deg[iS] : 0;
    float di = dinv[iS];
    short8 selfv = *(const short8*)(hb + (size_t)iS * 128 + ft * 8);
    float acc[8];
#pragma unroll
    for (int j = 0; j < 8; ++j) acc[j] = bs2f(selfv[j]);
    int mx = dg;
    mx = max(mx, __shfl_xor(mx, 16));
    mx = max(mx, __shfl_xor(mx, 32));
    for (int b = 0; b < mx; b += 16) {
      int rem = dg - b;
      int myidx = (ft < rem) ? col[s0 + b + ft] : 0;
#pragma unroll
      for (int k = 0; k < 16; ++k) {
        if (k < rem) {
          int ck = __shfl(myidx, (q << 4) + k);
          short8 r = *(const short8*)(hb + (size_t)ck * 128 + ft * 8);
#pragma unroll
          for (int j = 0; j < 8; ++j) acc[j] += bs2f(r[j]);
        }
      }
    }
    short8 o;
#pragma unroll
    for (int j = 0; j < 8; ++j) {
      float v = fmaxf(fmaf(acc[j], di, bb[j]), 0.f);
      o[j] = ok ? f2bs(v) : (short)0;
    }
    int byteoff = rl * 256 + ((ft * 16) ^ ((rl & 7) << 4));
    *(short8*)((char*)st + byteoff) = o;
  }
  __syncthreads();

  // ---- phase 2: MFMA over the staged tile ----
  int quad = lane >> 4;
  int rl2 = wave * 16 + (lane & 15);
  float4v acc2[NT];
#pragma unroll
  for (int t = 0; t < NT; ++t) acc2[t] = (float4v){0.f, 0.f, 0.f, 0.f};
#pragma unroll
  for (int kc = 0; kc < 4; ++kc) {
    int c0 = kc * 64 + quad * 16;
    short8 af = *(const short8*)((const char*)st + rl2 * 256 + (c0 ^ ((rl2 & 7) << 4)));
#pragma unroll
    for (int t = 0; t < NT; ++t) {
      short8 bfr = *(const short8*)(sw + (kc * NT + t) * 512 + lane * 8);
      acc2[t] = __builtin_amdgcn_mfma_f32_16x16x32_bf16(af, bfr, acc2[t], 0, 0, 0);
    }
  }
  int orow0 = blockIdx.x * 64 + wave * 16 + quad * 4;
  float dv[4] = {1.f, 1.f, 1.f, 1.f};
  if constexpr (SCALE) {
#pragma unroll
    for (int r = 0; r < 4; ++r) dv[r] = (orow0 + r < n) ? dscale[orow0 + r] : 0.f;
  }
#pragma unroll
  for (int t = 0; t < NT; ++t) {
    int ocol = t * 16 + (lane & 15);
#pragma unroll
    for (int r = 0; r < 4; ++r) {
      int orow = orow0 + r;
      if (orow < n) {
        float val = acc2[t][r];
        if constexpr (SCALE) val *= dv[r];
        if (FP32OUT)
          ((float*)Yv)[(size_t)orow * NT * 16 + ocol] = val;
        else
          ((__hip_bfloat16*)Yv)[(size_t)orow * NT * 16 + ocol] = (__hip_bfloat16)val;
      }
    }
  }
}

// ---------------- fused edge head: MFMA ea@We, + PQ[s] + PQ[d] + b, quad-shuffle log-softmax ----------------
__global__ __launch_bounds__(256) void edge_fused(const int* __restrict__ ei, const float* __restrict__ ea,
                                                  const short* __restrict__ wpe, const float* __restrict__ bfc,
                                                  const float* __restrict__ PQ, float* __restrict__ out, int E) {
  __shared__ short sw[512];
  __shared__ float sb[16];
  int tid = threadIdx.x;
  if (tid < 64) ((float4*)sw)[tid] = ((const float4*)wpe)[tid];
  if (tid < 16) sb[tid] = bfc[tid];
  __syncthreads();
  int wave = tid >> 6, lane = tid & 63, quad = lane >> 4;
  int row = blockIdx.x * 64 + wave * 16 + (lane & 15);
  short8 af = {0, 0, 0, 0, 0, 0, 0, 0};
  if (row < E) {
    const float* xp = ea + (size_t)row * D_E + quad * 8;
    float4 x0 = *(const float4*)xp;
    float4 x1 = *(const float4*)(xp + 4);
    af[0] = f2bs(x0.x); af[1] = f2bs(x0.y); af[2] = f2bs(x0.z); af[3] = f2bs(x0.w);
    af[4] = f2bs(x1.x); af[5] = f2bs(x1.y); af[6] = f2bs(x1.z); af[7] = f2bs(x1.w);
  }
  short8 bfr = *(const short8*)(sw + lane * 8);
  float4v acc = (float4v){0.f, 0.f, 0.f, 0.f};
  acc = __builtin_amdgcn_mfma_f32_16x16x32_bf16(af, bfr, acc, 0, 0, 0);
  int c = lane & 15;
  int orow0 = blockIdx.x * 64 + wave * 16 + quad * 4;
  float bb = sb[c];
  float ps[4], pd[4];
#pragma unroll
  for (int r = 0; r < 4; ++r) {
    int orow = orow0 + r;
    int er = (orow < E) ? orow : (E - 1);
    int s = ei[er], d = ei[E + er];
    ps[r] = PQ[(size_t)s * 32 + c];
    pd[r] = PQ[(size_t)d * 32 + 16 + c];
  }
#pragma unroll
  for (int r = 0; r < 4; ++r) {
    float l = acc[r] + bb + ps[r] + pd[r];
    float m = l;
#pragma unroll
    for (int w = 1; w < 16; w <<= 1) m = fmaxf(m, __shfl_xor(m, w));
    float ex = __expf(l - m);
    float sum = ex;
#pragma unroll
    for (int w = 1; w < 16; w <<= 1) sum += __shfl_xor(sum, w);
    float lse = __logf(sum) + m;
    int orow = orow0 + r;
    if (orow < E) out[(size_t)orow * NC + c] = l - lse;
  }
}

// ---------------- launch ----------------

extern "C" void kernel_launch(void* const* d_in, const int* in_sizes, int n_in,
                              void* d_out, int out_size, void* d_ws, size_t ws_size,
                              hipStream_t stream) {
  const float* x   = (const float*)d_in[0];
  const int*   ei  = (const int*)d_in[1];
  const float* ea  = (const float*)d_in[2];
  const float* W1  = (const float*)d_in[3];
  const float* b1  = (const float*)d_in[4];
  const float* W2  = (const float*)d_in[5];
  const float* b2  = (const float*)d_in[6];
  const float* W3  = (const float*)d_in[7];
  const float* b3  = (const float*)d_in[8];
  const float* Wfc = (const float*)d_in[9];
  const float* bfc = (const float*)d_in[10];
  float* out = (float*)d_out;
  int N = in_sizes[0] / D_IN;
  int E = in_sizes[1] / 2;

  char* w = (char*)d_ws;
  size_t off = 0;
  auto alloc = [&](size_t bytes) -> char* {
    char* p = w + off;
    off += (bytes + 255) & ~(size_t)255;
    return p;
  };
  __hip_bfloat16* A = (__hip_bfloat16*)alloc((size_t)N * HDIM * 2);  // 25.6 MB
  __hip_bfloat16* B = (__hip_bfloat16*)alloc((size_t)N * HDIM * 2);  // 25.6 MB
  float* PQ     = (float*)alloc((size_t)N * 32 * 4);                 // 12.8 MB
  int*   col    = (int*)alloc((size_t)E * 4 + 256);                  // +pad for batch reads
  int*   epos   = (int*)alloc((size_t)E * 4);
  int*   deg    = (int*)alloc((size_t)N * 4);
  float* dinv   = (float*)alloc((size_t)N * 4);
  int*   rowptr = (int*)alloc((size_t)N * 4);
  int*   bsum   = (int*)alloc(1024 * 4);
  int*   boff   = (int*)alloc(1024 * 4);
  short* wp1    = (short*)alloc(16384 * 2);
  short* wp2    = (short*)alloc(16384 * 2);
  short* wp3    = (short*)alloc(16384 * 2);
  short* wpc    = (short*)alloc(4096 * 2);
  short* wpe    = (short*)alloc(512 * 2);

  hipMemsetAsync(deg, 0, (size_t)N * 4, stream);

  int eb = (E + 255) / 256;
  int sb = (N + SCAN_CHUNK - 1) / SCAN_CHUNK;
  count_deg<<<eb, 256, 0, stream>>>(ei, deg, epos, E);
  scan_blocksums<<<sb, 256, 0, stream>>>(deg, bsum, N);
  scan_offsets<<<1, 256, 0, stream>>>(bsum, boff, sb);
  scan_write<<<sb, 256, 0, stream>>>(deg, boff, rowptr, dinv, N);
  fill_csr<<<eb, 256, 0, stream>>>(ei, rowptr, epos, col, E);
  repack_w128<<<64, 256, 0, stream>>>(W1, wp1);
  repack_w128<<<64, 256, 0, stream>>>(W2, wp2);
  repack_w128<<<64, 256, 0, stream>>>(W3, wp3);
  repack_wcp<<<16, 256, 0, stream>>>(Wfc, wpc);
  repack_wea<<<2, 256, 0, stream>>>(Wfc, wpe);

  int gb = (N + 63) / 64;
  int geb = (E + 63) / 64;
  gemm_l1<<<gb, 256, 0, stream>>>(x, wp1, A, dinv, N);
  agg_gemm<8, false, true ><<<gb, 256, 0, stream>>>(A, dinv, rowptr, deg, col, b1, wp2, B, dinv, N);
  agg_gemm<8, false, true ><<<gb, 256, 0, stream>>>(B, dinv, rowptr, deg, col, b2, wp3, A, dinv, N);
  agg_gemm<2, true,  false><<<gb, 256, 0, stream>>>(A, dinv, rowptr, deg, col, b3, wpc, PQ, nullptr, N);
  edge_fused<<<geb, 256, 0, stream>>>(ei, ea, wpe, bfc, PQ, out, E);
}

// Round 7
// 564.934 us; speedup vs baseline: 1.1114x; 1.1114x over previous
//
#include <hip/hip_runtime.h>
#include <hip/hip_bf16.h>

#define D_IN 128
#define HDIM 128
#define D_E  32
#define NC   16
#define SCAN_CHUNK 2048

typedef __attribute__((ext_vector_type(8))) short short8;
typedef __attribute__((ext_vector_type(4))) float float4v;

__device__ inline short f2bs(float f) {
  __hip_bfloat16 h = (__hip_bfloat16)f;
  return *reinterpret_cast<short*>(&h);
}

__device__ inline float bs2f(short s) {
  unsigned int u = ((unsigned int)(unsigned short)s) << 16;
  float f;
  __builtin_memcpy(&f, &u, 4);
  return f;
}

// ---------------- prologue: degree, CSR ----------------

// also records each edge's arrival slot so fill_csr needs no second atomic pass
__global__ __launch_bounds__(256) void count_deg(const int* __restrict__ ei, int* __restrict__ deg,
                                                 int* __restrict__ epos, int E) {
  int e = blockIdx.x * 256 + threadIdx.x;
  if (e < E) epos[e] = atomicAdd(&deg[ei[E + e]], 1);
}

__global__ __launch_bounds__(256) void scan_blocksums(const int* __restrict__ deg, int* __restrict__ bsum, int n) {
  __shared__ int red[256];
  int t = threadIdx.x;
  int base = blockIdx.x * SCAN_CHUNK + t * 8;
  int s = 0;
#pragma unroll
  for (int j = 0; j < 8; ++j) {
    int i = base + j;
    if (i < n) s += deg[i];
  }
  red[t] = s;
  __syncthreads();
  for (int off = 128; off > 0; off >>= 1) {
    if (t < off) red[t] += red[t + off];
    __syncthreads();
  }
  if (t == 0) bsum[blockIdx.x] = red[0];
}

__global__ __launch_bounds__(256) void scan_offsets(const int* __restrict__ bsum, int* __restrict__ boff, int nb) {
  __shared__ int s[256];
  int t = threadIdx.x;
  int v = (t < nb) ? bsum[t] : 0;
  s[t] = v;
  __syncthreads();
  for (int off = 1; off < 256; off <<= 1) {
    int u = (t >= off) ? s[t - off] : 0;
    __syncthreads();
    s[t] += u;
    __syncthreads();
  }
  if (t < nb) boff[t] = (t == 0) ? 0 : s[t - 1];
}

__global__ __launch_bounds__(256) void scan_write(const int* __restrict__ deg, const int* __restrict__ boff,
                                                  int* __restrict__ rowptr, float* __restrict__ dinv, int n) {
  __shared__ int red[256];
  int t = threadIdx.x;
  int base = blockIdx.x * SCAN_CHUNK + t * 8;
  int v[8];
  int s = 0;
#pragma unroll
  for (int j = 0; j < 8; ++j) {
    int i = base + j;
    v[j] = (i < n) ? deg[i] : 0;
    s += v[j];
  }
  red[t] = s;
  __syncthreads();
  for (int off = 1; off < 256; off <<= 1) {
    int u = (t >= off) ? red[t - off] : 0;
    __syncthreads();
    red[t] += u;
    __syncthreads();
  }
  int run = red[t] - s + boff[blockIdx.x];
#pragma unroll
  for (int j = 0; j < 8; ++j) {
    int i = base + j;
    if (i < n) {
      rowptr[i] = run;
      dinv[i] = rsqrtf((float)v[j] + 1.0f);
    }
    run += v[j];
  }
}

__global__ __launch_bounds__(256) void fill_csr(const int* __restrict__ ei, const int* __restrict__ rowptr,
                                                const int* __restrict__ epos, int* __restrict__ col, int E) {
  int e = blockIdx.x * 256 + threadIdx.x;
  if (e < E) {
    int d = ei[E + e];
    col[rowptr[d] + epos[e]] = ei[e];
  }
}

// ---------------- weight repack into MFMA B-fragment order (bf16) ----------------
__global__ __launch_bounds__(256) void repack_w128(const float* __restrict__ W, short* __restrict__ wp) {
  int idx = blockIdx.x * 256 + threadIdx.x;  // 4*8*64*8 = 16384
  if (idx < 16384) {
    int j = idx & 7, lane = (idx >> 3) & 63, t = (idx >> 9) & 7, kc = idx >> 12;
    int k = kc * 32 + (lane >> 4) * 8 + j;
    int nn = t * 16 + (lane & 15);
    wp[idx] = f2bs(W[k * HDIM + nn]);
  }
}

__global__ __launch_bounds__(256) void repack_wcp(const float* __restrict__ Wfc, short* __restrict__ wp) {
  int idx = blockIdx.x * 256 + threadIdx.x;  // 4*2*64*8 = 4096
  if (idx < 4096) {
    int j = idx & 7, lane = (idx >> 3) & 63, t = (idx >> 9) & 1, kc = idx >> 10;
    int k = kc * 32 + (lane >> 4) * 8 + j;
    int nn = t * 16 + (lane & 15);
    float v = (nn < 16) ? Wfc[k * NC + nn] : Wfc[(HDIM + k) * NC + (nn - 16)];
    wp[idx] = f2bs(v);
  }
}

// Pack Wfc rows 256..287 (edge_attr block), K=32, 16 cols
__global__ __launch_bounds__(256) void repack_wea(const float* __restrict__ Wfc, short* __restrict__ wp) {
  int idx = blockIdx.x * 256 + threadIdx.x;  // 512
  if (idx < 512) {
    int j = idx & 7, lane = (idx >> 3) & 63;
    int k = (lane >> 4) * 8 + j;
    int nn = lane & 15;
    wp[idx] = f2bs(Wfc[(2 * HDIM + k) * NC + nn]);
  }
}

// ---------------- MFMA GEMM (layer 1 only): Y[n x 128] = X[n x 128] @ W, fp32 in ----------------
__global__ __launch_bounds__(256) void gemm_l1(const float* __restrict__ Xv, const short* __restrict__ wpack,
                                               __hip_bfloat16* __restrict__ Yv, const float* __restrict__ dscale, int n) {
  constexpr int NT = 8;
  __shared__ short sw[4 * NT * 512];
  int tid = threadIdx.x;
  {
    const float4* wg = (const float4*)wpack;
    float4* sg = (float4*)sw;
    for (int i = tid; i < 4 * NT * 512 / 8; i += 256) sg[i] = wg[i];
  }
  __syncthreads();
  int wave = tid >> 6, lane = tid & 63;
  int quad = lane >> 4;
  int row = blockIdx.x * 64 + wave * 16 + (lane & 15);
  bool rowok = row < n;
  float4v acc[NT];
#pragma unroll
  for (int t = 0; t < NT; ++t) acc[t] = (float4v){0.f, 0.f, 0.f, 0.f};

#pragma unroll
  for (int kc = 0; kc < 4; ++kc) {
    short8 af = {0, 0, 0, 0, 0, 0, 0, 0};
    if (rowok) {
      const float* xp = Xv + (size_t)row * 128 + kc * 32 + quad * 8;
      float4 x0 = *(const float4*)xp;
      float4 x1 = *(const float4*)(xp + 4);
      af[0] = f2bs(x0.x); af[1] = f2bs(x0.y); af[2] = f2bs(x0.z); af[3] = f2bs(x0.w);
      af[4] = f2bs(x1.x); af[5] = f2bs(x1.y); af[6] = f2bs(x1.z); af[7] = f2bs(x1.w);
    }
#pragma unroll
    for (int t = 0; t < NT; ++t) {
      short8 bfr = *(const short8*)(sw + (kc * NT + t) * 512 + lane * 8);
      acc[t] = __builtin_amdgcn_mfma_f32_16x16x32_bf16(af, bfr, acc[t], 0, 0, 0);
    }
  }
  int orow0 = blockIdx.x * 64 + wave * 16 + quad * 4;
  float dv[4];
#pragma unroll
  for (int r = 0; r < 4; ++r) dv[r] = (orow0 + r < n) ? dscale[orow0 + r] : 0.f;
#pragma unroll
  for (int t = 0; t < NT; ++t) {
    int ocol = t * 16 + (lane & 15);
#pragma unroll
    for (int r = 0; r < 4; ++r) {
      int orow = orow0 + r;
      if (orow < n) Yv[(size_t)orow * 128 + ocol] = (__hip_bfloat16)(acc[t][r] * dv[r]);
    }
  }
}

// ---------------- FUSED aggregation + GEMM (occupancy-fixed) ----------------
// Round-6 lesson: the 32KB weight stage capped residency at 3 blocks/CU and the gather
// phase is latency-bound -> starved. Weights are now read DIRECTLY from global in the
// MFMA loop (32KB, identical across blocks -> L1/L2-hot after first touch per CU).
// LDS = 16KB row tile only -> ~7 blocks/CU for the gather phase.
template<int NT, bool FP32OUT, bool SCALE>
__global__ __launch_bounds__(256) void agg_gemm(const __hip_bfloat16* __restrict__ hs, const float* __restrict__ dinv,
                                                const int* __restrict__ rowptr, const int* __restrict__ deg,
                                                const int* __restrict__ col, const float* __restrict__ bias,
                                                const short* __restrict__ wpack, void* __restrict__ Yv,
                                                const float* __restrict__ dscale, int n) {
  __shared__ short st[64 * 128];  // 16 KB staged rows (swizzled)
  int tid = threadIdx.x;
  int wave = tid >> 6, lane = tid & 63;
  int q = lane >> 4, ft = lane & 15;
  const short* hb = (const short*)hs;
  float4 b0 = *(const float4*)(bias + ft * 8);
  float4 b1 = *(const float4*)(bias + ft * 8 + 4);
  float bb[8] = {b0.x, b0.y, b0.z, b0.w, b1.x, b1.y, b1.z, b1.w};

  // ---- phase 1: aggregate 4 passes x 4 nodes per wave = 16 rows per wave ----
  for (int p = 0; p < 4; ++p) {
    int rl = wave * 16 + p * 4 + q;            // local row 0..63
    int i = blockIdx.x * 64 + rl;
    bool ok = i < n;
    int iS = ok ? i : (n - 1);
    int s0 = rowptr[iS];
    int dg = ok ? deg[iS] : 0;
    float di = dinv[iS];
    short8 selfv = *(const short8*)(hb + (size_t)iS * 128 + ft * 8);
    float acc[8];
#pragma unroll
    for (int j = 0; j < 8; ++j) acc[j] = bs2f(selfv[j]);
    int mx = dg;
    mx = max(mx, __shfl_xor(mx, 16));
    mx = max(mx, __shfl_xor(mx, 32));
    for (int b = 0; b < mx; b += 16) {
      int rem = dg - b;
      int myidx = (ft < rem) ? col[s0 + b + ft] : 0;
#pragma unroll
      for (int k = 0; k < 16; ++k) {
        if (k < rem) {
          int ck = __shfl(myidx, (q << 4) + k);
          short8 r = *(const short8*)(hb + (size_t)ck * 128 + ft * 8);
#pragma unroll
          for (int j = 0; j < 8; ++j) acc[j] += bs2f(r[j]);
        }
      }
    }
    short8 o;
#pragma unroll
    for (int j = 0; j < 8; ++j) {
      float v = fmaxf(fmaf(acc[j], di, bb[j]), 0.f);
      o[j] = ok ? f2bs(v) : (short)0;
    }
    int byteoff = rl * 256 + ((ft * 16) ^ ((rl & 7) << 4));
    *(short8*)((char*)st + byteoff) = o;
  }
  __syncthreads();

  // ---- phase 2: MFMA over the staged tile, weights straight from global (L2-hot) ----
  int quad = lane >> 4;
  int rl2 = wave * 16 + (lane & 15);
  float4v acc2[NT];
#pragma unroll
  for (int t = 0; t < NT; ++t) acc2[t] = (float4v){0.f, 0.f, 0.f, 0.f};
#pragma unroll
  for (int kc = 0; kc < 4; ++kc) {
    int c0 = kc * 64 + quad * 16;
    short8 af = *(const short8*)((const char*)st + rl2 * 256 + (c0 ^ ((rl2 & 7) << 4)));
#pragma unroll
    for (int t = 0; t < NT; ++t) {
      short8 bfr = *(const short8*)(wpack + (kc * NT + t) * 512 + lane * 8);
      acc2[t] = __builtin_amdgcn_mfma_f32_16x16x32_bf16(af, bfr, acc2[t], 0, 0, 0);
    }
  }
  int orow0 = blockIdx.x * 64 + wave * 16 + quad * 4;
  float dv[4] = {1.f, 1.f, 1.f, 1.f};
  if constexpr (SCALE) {
#pragma unroll
    for (int r = 0; r < 4; ++r) dv[r] = (orow0 + r < n) ? dscale[orow0 + r] : 0.f;
  }
#pragma unroll
  for (int t = 0; t < NT; ++t) {
    int ocol = t * 16 + (lane & 15);
#pragma unroll
    for (int r = 0; r < 4; ++r) {
      int orow = orow0 + r;
      if (orow < n) {
        float val = acc2[t][r];
        if constexpr (SCALE) val *= dv[r];
        if (FP32OUT)
          ((float*)Yv)[(size_t)orow * NT * 16 + ocol] = val;
        else
          ((__hip_bfloat16*)Yv)[(size_t)orow * NT * 16 + ocol] = (__hip_bfloat16)val;
      }
    }
  }
}

// ---------------- fused edge head: MFMA ea@We, + PQ[s] + PQ[d] + b, quad-shuffle log-softmax ----------------
__global__ __launch_bounds__(256) void edge_fused(const int* __restrict__ ei, const float* __restrict__ ea,
                                                  const short* __restrict__ wpe, const float* __restrict__ bfc,
                                                  const float* __restrict__ PQ, float* __restrict__ out, int E) {
  __shared__ short sw[512];
  __shared__ float sb[16];
  int tid = threadIdx.x;
  if (tid < 64) ((float4*)sw)[tid] = ((const float4*)wpe)[tid];
  if (tid < 16) sb[tid] = bfc[tid];
  __syncthreads();
  int wave = tid >> 6, lane = tid & 63, quad = lane >> 4;
  int row = blockIdx.x * 64 + wave * 16 + (lane & 15);
  short8 af = {0, 0, 0, 0, 0, 0, 0, 0};
  if (row < E) {
    const float* xp = ea + (size_t)row * D_E + quad * 8;
    float4 x0 = *(const float4*)xp;
    float4 x1 = *(const float4*)(xp + 4);
    af[0] = f2bs(x0.x); af[1] = f2bs(x0.y); af[2] = f2bs(x0.z); af[3] = f2bs(x0.w);
    af[4] = f2bs(x1.x); af[5] = f2bs(x1.y); af[6] = f2bs(x1.z); af[7] = f2bs(x1.w);
  }
  short8 bfr = *(const short8*)(sw + lane * 8);
  float4v acc = (float4v){0.f, 0.f, 0.f, 0.f};
  acc = __builtin_amdgcn_mfma_f32_16x16x32_bf16(af, bfr, acc, 0, 0, 0);
  int c = lane & 15;
  int orow0 = blockIdx.x * 64 + wave * 16 + quad * 4;
  float bb = sb[c];
  float ps[4], pd[4];
#pragma unroll
  for (int r = 0; r < 4; ++r) {
    int orow = orow0 + r;
    int er = (orow < E) ? orow : (E - 1);
    int s = ei[er], d = ei[E + er];
    ps[r] = PQ[(size_t)s * 32 + c];
    pd[r] = PQ[(size_t)d * 32 + 16 + c];
  }
#pragma unroll
  for (int r = 0; r < 4; ++r) {
    float l = acc[r] + bb + ps[r] + pd[r];
    float m = l;
#pragma unroll
    for (int w = 1; w < 16; w <<= 1) m = fmaxf(m, __shfl_xor(m, w));
    float ex = __expf(l - m);
    float sum = ex;
#pragma unroll
    for (int w = 1; w < 16; w <<= 1) sum += __shfl_xor(sum, w);
    float lse = __logf(sum) + m;
    int orow = orow0 + r;
    if (orow < E) out[(size_t)orow * NC + c] = l - lse;
  }
}

// ---------------- launch ----------------

extern "C" void kernel_launch(void* const* d_in, const int* in_sizes, int n_in,
                              void* d_out, int out_size, void* d_ws, size_t ws_size,
                              hipStream_t stream) {
  const float* x   = (const float*)d_in[0];
  const int*   ei  = (const int*)d_in[1];
  const float* ea  = (const float*)d_in[2];
  const float* W1  = (const float*)d_in[3];
  const float* b1  = (const float*)d_in[4];
  const float* W2  = (const float*)d_in[5];
  const float* b2  = (const float*)d_in[6];
  const float* W3  = (const float*)d_in[7];
  const float* b3  = (const float*)d_in[8];
  const float* Wfc = (const float*)d_in[9];
  const float* bfc = (const float*)d_in[10];
  float* out = (float*)d_out;
  int N = in_sizes[0] / D_IN;
  int E = in_sizes[1] / 2;

  char* w = (char*)d_ws;
  size_t off = 0;
  auto alloc = [&](size_t bytes) -> char* {
    char* p = w + off;
    off += (bytes + 255) & ~(size_t)255;
    return p;
  };
  __hip_bfloat16* A = (__hip_bfloat16*)alloc((size_t)N * HDIM * 2);  // 25.6 MB
  __hip_bfloat16* B = (__hip_bfloat16*)alloc((size_t)N * HDIM * 2);  // 25.6 MB
  float* PQ     = (float*)alloc((size_t)N * 32 * 4);                 // 12.8 MB
  int*   col    = (int*)alloc((size_t)E * 4 + 256);                  // +pad for batch reads
  int*   epos   = (int*)alloc((size_t)E * 4);
  int*   deg    = (int*)alloc((size_t)N * 4);
  float* dinv   = (float*)alloc((size_t)N * 4);
  int*   rowptr = (int*)alloc((size_t)N * 4);
  int*   bsum   = (int*)alloc(1024 * 4);
  int*   boff   = (int*)alloc(1024 * 4);
  short* wp1    = (short*)alloc(16384 * 2);
  short* wp2    = (short*)alloc(16384 * 2);
  short* wp3    = (short*)alloc(16384 * 2);
  short* wpc    = (short*)alloc(4096 * 2);
  short* wpe    = (short*)alloc(512 * 2);

  hipMemsetAsync(deg, 0, (size_t)N * 4, stream);

  int eb = (E + 255) / 256;
  int sb = (N + SCAN_CHUNK - 1) / SCAN_CHUNK;
  count_deg<<<eb, 256, 0, stream>>>(ei, deg, epos, E);
  scan_blocksums<<<sb, 256, 0, stream>>>(deg, bsum, N);
  scan_offsets<<<1, 256, 0, stream>>>(bsum, boff, sb);
  scan_write<<<sb, 256, 0, stream>>>(deg, boff, rowptr, dinv, N);
  fill_csr<<<eb, 256, 0, stream>>>(ei, rowptr, epos, col, E);
  repack_w128<<<64, 256, 0, stream>>>(W1, wp1);
  repack_w128<<<64, 256, 0, stream>>>(W2, wp2);
  repack_w128<<<64, 256, 0, stream>>>(W3, wp3);
  repack_wcp<<<16, 256, 0, stream>>>(Wfc, wpc);
  repack_wea<<<2, 256, 0, stream>>>(Wfc, wpe);

  int gb = (N + 63) / 64;
  int geb = (E + 63) / 64;
  gemm_l1<<<gb, 256, 0, stream>>>(x, wp1, A, dinv, N);
  agg_gemm<8, false, true ><<<gb, 256, 0, stream>>>(A, dinv, rowptr, deg, col, b1, wp2, B, dinv, N);
  agg_gemm<8, false, true ><<<gb, 256, 0, stream>>>(B, dinv, rowptr, deg, col, b2, wp3, A, dinv, N);
  agg_gemm<2, true,  false><<<gb, 256, 0, stream>>>(A, dinv, rowptr, deg, col, b3, wpc, PQ, nullptr, N);
  edge_fused<<<geb, 256, 0, stream>>>(ei, ea, wpe, bfc, PQ, out, E);
}

// Round 8
// 526.029 us; speedup vs baseline: 1.1936x; 1.0740x over previous
//
#include <hip/hip_runtime.h>
#include <hip/hip_bf16.h>

#define D_IN 128
#define HDIM 128
#define D_E  32
#define NC   16
#define SCAN_CHUNK 2048

typedef __attribute__((ext_vector_type(8))) short short8;
typedef __attribute__((ext_vector_type(4))) float float4v;

__device__ inline short f2bs(float f) {
  __hip_bfloat16 h = (__hip_bfloat16)f;
  return *reinterpret_cast<short*>(&h);
}

__device__ inline float bs2f(short s) {
  unsigned int u = ((unsigned int)(unsigned short)s) << 16;
  float f;
  __builtin_memcpy(&f, &u, 4);
  return f;
}

// ---------------- prologue: degree, CSR ----------------

__global__ __launch_bounds__(256) void count_deg(const int* __restrict__ ei, int* __restrict__ deg,
                                                 int* __restrict__ epos, int E) {
  int e = blockIdx.x * 256 + threadIdx.x;
  if (e < E) epos[e] = atomicAdd(&deg[ei[E + e]], 1);
}

__global__ __launch_bounds__(256) void scan_blocksums(const int* __restrict__ deg, int* __restrict__ bsum, int n) {
  __shared__ int red[256];
  int t = threadIdx.x;
  int base = blockIdx.x * SCAN_CHUNK + t * 8;
  int s = 0;
#pragma unroll
  for (int j = 0; j < 8; ++j) {
    int i = base + j;
    if (i < n) s += deg[i];
  }
  red[t] = s;
  __syncthreads();
  for (int off = 128; off > 0; off >>= 1) {
    if (t < off) red[t] += red[t + off];
    __syncthreads();
  }
  if (t == 0) bsum[blockIdx.x] = red[0];
}

__global__ __launch_bounds__(256) void scan_offsets(const int* __restrict__ bsum, int* __restrict__ boff, int nb) {
  __shared__ int s[256];
  int t = threadIdx.x;
  int v = (t < nb) ? bsum[t] : 0;
  s[t] = v;
  __syncthreads();
  for (int off = 1; off < 256; off <<= 1) {
    int u = (t >= off) ? s[t - off] : 0;
    __syncthreads();
    s[t] += u;
    __syncthreads();
  }
  if (t < nb) boff[t] = (t == 0) ? 0 : s[t - 1];
}

__global__ __launch_bounds__(256) void scan_write(const int* __restrict__ deg, const int* __restrict__ boff,
                                                  int* __restrict__ rowptr, float* __restrict__ dinv, int n) {
  __shared__ int red[256];
  int t = threadIdx.x;
  int base = blockIdx.x * SCAN_CHUNK + t * 8;
  int v[8];
  int s = 0;
#pragma unroll
  for (int j = 0; j < 8; ++j) {
    int i = base + j;
    v[j] = (i < n) ? deg[i] : 0;
    s += v[j];
  }
  red[t] = s;
  __syncthreads();
  for (int off = 1; off < 256; off <<= 1) {
    int u = (t >= off) ? red[t - off] : 0;
    __syncthreads();
    red[t] += u;
    __syncthreads();
  }
  int run = red[t] - s + boff[blockIdx.x];
#pragma unroll
  for (int j = 0; j < 8; ++j) {
    int i = base + j;
    if (i < n) {
      rowptr[i] = run;
      dinv[i] = rsqrtf((float)v[j] + 1.0f);
    }
    run += v[j];
  }
}

__global__ __launch_bounds__(256) void fill_csr(const int* __restrict__ ei, const int* __restrict__ rowptr,
                                                const int* __restrict__ epos, int* __restrict__ col, int E) {
  int e = blockIdx.x * 256 + threadIdx.x;
  if (e < E) {
    int d = ei[E + e];
    col[rowptr[d] + epos[e]] = ei[e];
  }
}

// ---------------- weight repack into MFMA B-fragment order (bf16) ----------------
__global__ __launch_bounds__(256) void repack_w128(const float* __restrict__ W, short* __restrict__ wp) {
  int idx = blockIdx.x * 256 + threadIdx.x;  // 4*8*64*8 = 16384
  if (idx < 16384) {
    int j = idx & 7, lane = (idx >> 3) & 63, t = (idx >> 9) & 7, kc = idx >> 12;
    int k = kc * 32 + (lane >> 4) * 8 + j;
    int nn = t * 16 + (lane & 15);
    wp[idx] = f2bs(W[k * HDIM + nn]);
  }
}

__global__ __launch_bounds__(256) void repack_wcp(const float* __restrict__ Wfc, short* __restrict__ wp) {
  int idx = blockIdx.x * 256 + threadIdx.x;  // 4*2*64*8 = 4096
  if (idx < 4096) {
    int j = idx & 7, lane = (idx >> 3) & 63, t = (idx >> 9) & 1, kc = idx >> 10;
    int k = kc * 32 + (lane >> 4) * 8 + j;
    int nn = t * 16 + (lane & 15);
    float v = (nn < 16) ? Wfc[k * NC + nn] : Wfc[(HDIM + k) * NC + (nn - 16)];
    wp[idx] = f2bs(v);
  }
}

// Pack Wfc rows 256..287 (edge_attr block), K=32, 16 cols
__global__ __launch_bounds__(256) void repack_wea(const float* __restrict__ Wfc, short* __restrict__ wp) {
  int idx = blockIdx.x * 256 + threadIdx.x;  // 512
  if (idx < 512) {
    int j = idx & 7, lane = (idx >> 3) & 63;
    int k = (lane >> 4) * 8 + j;
    int nn = lane & 15;
    wp[idx] = f2bs(Wfc[(2 * HDIM + k) * NC + nn]);
  }
}

// ---------------- MFMA GEMM (layer 1 only): Y[n x 128] = X[n x 128] @ W, fp32 in ----------------
__global__ __launch_bounds__(256) void gemm_l1(const float* __restrict__ Xv, const short* __restrict__ wpack,
                                               __hip_bfloat16* __restrict__ Yv, const float* __restrict__ dscale, int n) {
  constexpr int NT = 8;
  __shared__ short sw[4 * NT * 512];
  int tid = threadIdx.x;
  {
    const float4* wg = (const float4*)wpack;
    float4* sg = (float4*)sw;
    for (int i = tid; i < 4 * NT * 512 / 8; i += 256) sg[i] = wg[i];
  }
  __syncthreads();
  int wave = tid >> 6, lane = tid & 63;
  int quad = lane >> 4;
  int row = blockIdx.x * 64 + wave * 16 + (lane & 15);
  bool rowok = row < n;
  float4v acc[NT];
#pragma unroll
  for (int t = 0; t < NT; ++t) acc[t] = (float4v){0.f, 0.f, 0.f, 0.f};

#pragma unroll
  for (int kc = 0; kc < 4; ++kc) {
    short8 af = {0, 0, 0, 0, 0, 0, 0, 0};
    if (rowok) {
      const float* xp = Xv + (size_t)row * 128 + kc * 32 + quad * 8;
      float4 x0 = *(const float4*)xp;
      float4 x1 = *(const float4*)(xp + 4);
      af[0] = f2bs(x0.x); af[1] = f2bs(x0.y); af[2] = f2bs(x0.z); af[3] = f2bs(x0.w);
      af[4] = f2bs(x1.x); af[5] = f2bs(x1.y); af[6] = f2bs(x1.z); af[7] = f2bs(x1.w);
    }
#pragma unroll
    for (int t = 0; t < NT; ++t) {
      short8 bfr = *(const short8*)(sw + (kc * NT + t) * 512 + lane * 8);
      acc[t] = __builtin_amdgcn_mfma_f32_16x16x32_bf16(af, bfr, acc[t], 0, 0, 0);
    }
  }
  int orow0 = blockIdx.x * 64 + wave * 16 + quad * 4;
  float dv[4];
#pragma unroll
  for (int r = 0; r < 4; ++r) dv[r] = (orow0 + r < n) ? dscale[orow0 + r] : 0.f;
#pragma unroll
  for (int t = 0; t < NT; ++t) {
    int ocol = t * 16 + (lane & 15);
#pragma unroll
    for (int r = 0; r < 4; ++r) {
      int orow = orow0 + r;
      if (orow < n) Yv[(size_t)orow * 128 + ocol] = (__hip_bfloat16)(acc[t][r] * dv[r]);
    }
  }
}

// ---------------- FUSED aggregation + GEMM, 512-thread / 8-wave version ----------------
// Round-7 lesson: 4-wave blocks gave only 6252 waves total (occupancy 31%) -> gather
// latency not hidden. Now 8 waves/block, 8 rows/wave in phase 1 (2 passes x 4 nodes)
// -> 12504 waves. Phase 2 splits MFMA by column halves: wave w -> row-group (w&3),
// col-half (w>>2), NT/2 tiles each; accumulator halves (-16 VGPR), keeping VGPR<=64
// so 8 waves/SIMD stays legal. Weights read direct from global (L2-hot).
template<int NT, bool FP32OUT, bool SCALE>
__global__ __launch_bounds__(512) void agg_gemm(const __hip_bfloat16* __restrict__ hs, const float* __restrict__ dinv,
                                                const int* __restrict__ rowptr, const int* __restrict__ deg,
                                                const int* __restrict__ col, const float* __restrict__ bias,
                                                const short* __restrict__ wpack, void* __restrict__ Yv,
                                                const float* __restrict__ dscale, int n) {
  constexpr int NTH = NT / 2;
  __shared__ short st[64 * 128];  // 16 KB staged rows (swizzled)
  int tid = threadIdx.x;
  int wave = tid >> 6, lane = tid & 63;
  int q = lane >> 4, ft = lane & 15;
  const short* hb = (const short*)hs;
  float4 b0 = *(const float4*)(bias + ft * 8);
  float4 b1 = *(const float4*)(bias + ft * 8 + 4);
  float bb[8] = {b0.x, b0.y, b0.z, b0.w, b1.x, b1.y, b1.z, b1.w};

  // ---- phase 1: 2 passes x 4 nodes per wave = 8 rows per wave, 64 rows per block ----
  for (int p = 0; p < 2; ++p) {
    int rl = wave * 8 + p * 4 + q;             // local row 0..63
    int i = blockIdx.x * 64 + rl;
    bool ok = i < n;
    int iS = ok ? i : (n - 1);
    int s0 = rowptr[iS];
    int dg = ok ? deg[iS] : 0;
    float di = dinv[iS];
    short8 selfv = *(const short8*)(hb + (size_t)iS * 128 + ft * 8);
    float acc[8];
#pragma unroll
    for (int j = 0; j < 8; ++j) acc[j] = bs2f(selfv[j]);
    int mx = dg;
    mx = max(mx, __shfl_xor(mx, 16));
    mx = max(mx, __shfl_xor(mx, 32));
    for (int b = 0; b < mx; b += 16) {
      int rem = dg - b;
      int myidx = (ft < rem) ? col[s0 + b + ft] : 0;
#pragma unroll
      for (int k = 0; k < 16; ++k) {
        if (k < rem) {
          int ck = __shfl(myidx, (q << 4) + k);
          short8 r = *(const short8*)(hb + (size_t)ck * 128 + ft * 8);
#pragma unroll
          for (int j = 0; j < 8; ++j) acc[j] += bs2f(r[j]);
        }
      }
    }
    short8 o;
#pragma unroll
    for (int j = 0; j < 8; ++j) {
      float v = fmaxf(fmaf(acc[j], di, bb[j]), 0.f);
      o[j] = ok ? f2bs(v) : (short)0;
    }
    int byteoff = rl * 256 + ((ft * 16) ^ ((rl & 7) << 4));
    *(short8*)((char*)st + byteoff) = o;
  }
  __syncthreads();

  // ---- phase 2: wave w -> rows (w&3)*16..+16, cols (w>>2)*NTH*16..; weights from global ----
  int rg = wave & 3, ch = wave >> 2;
  int quad = lane >> 4;
  int rl2 = rg * 16 + (lane & 15);
  float4v acc2[NTH];
#pragma unroll
  for (int t = 0; t < NTH; ++t) acc2[t] = (float4v){0.f, 0.f, 0.f, 0.f};
#pragma unroll
  for (int kc = 0; kc < 4; ++kc) {
    int c0 = kc * 64 + quad * 16;
    short8 af = *(const short8*)((const char*)st + rl2 * 256 + (c0 ^ ((rl2 & 7) << 4)));
#pragma unroll
    for (int t = 0; t < NTH; ++t) {
      short8 bfr = *(const short8*)(wpack + (kc * NT + ch * NTH + t) * 512 + lane * 8);
      acc2[t] = __builtin_amdgcn_mfma_f32_16x16x32_bf16(af, bfr, acc2[t], 0, 0, 0);
    }
  }
  int orow0 = blockIdx.x * 64 + rg * 16 + quad * 4;
  float dv[4] = {1.f, 1.f, 1.f, 1.f};
  if constexpr (SCALE) {
#pragma unroll
    for (int r = 0; r < 4; ++r) dv[r] = (orow0 + r < n) ? dscale[orow0 + r] : 0.f;
  }
#pragma unroll
  for (int t = 0; t < NTH; ++t) {
    int ocol = ch * (NTH * 16) + t * 16 + (lane & 15);
#pragma unroll
    for (int r = 0; r < 4; ++r) {
      int orow = orow0 + r;
      if (orow < n) {
        float val = acc2[t][r];
        if constexpr (SCALE) val *= dv[r];
        if (FP32OUT)
          ((float*)Yv)[(size_t)orow * NT * 16 + ocol] = val;
        else
          ((__hip_bfloat16*)Yv)[(size_t)orow * NT * 16 + ocol] = (__hip_bfloat16)val;
      }
    }
  }
}

// ---------------- fused edge head: MFMA ea@We, + PQ[s] + PQ[d] + b, quad-shuffle log-softmax ----------------
__global__ __launch_bounds__(256) void edge_fused(const int* __restrict__ ei, const float* __restrict__ ea,
                                                  const short* __restrict__ wpe, const float* __restrict__ bfc,
                                                  const float* __restrict__ PQ, float* __restrict__ out, int E) {
  __shared__ short sw[512];
  __shared__ float sb[16];
  int tid = threadIdx.x;
  if (tid < 64) ((float4*)sw)[tid] = ((const float4*)wpe)[tid];
  if (tid < 16) sb[tid] = bfc[tid];
  __syncthreads();
  int wave = tid >> 6, lane = tid & 63, quad = lane >> 4;
  int row = blockIdx.x * 64 + wave * 16 + (lane & 15);
  short8 af = {0, 0, 0, 0, 0, 0, 0, 0};
  if (row < E) {
    const float* xp = ea + (size_t)row * D_E + quad * 8;
    float4 x0 = *(const float4*)xp;
    float4 x1 = *(const float4*)(xp + 4);
    af[0] = f2bs(x0.x); af[1] = f2bs(x0.y); af[2] = f2bs(x0.z); af[3] = f2bs(x0.w);
    af[4] = f2bs(x1.x); af[5] = f2bs(x1.y); af[6] = f2bs(x1.z); af[7] = f2bs(x1.w);
  }
  short8 bfr = *(const short8*)(sw + lane * 8);
  float4v acc = (float4v){0.f, 0.f, 0.f, 0.f};
  acc = __builtin_amdgcn_mfma_f32_16x16x32_bf16(af, bfr, acc, 0, 0, 0);
  int c = lane & 15;
  int orow0 = blockIdx.x * 64 + wave * 16 + quad * 4;
  float bb = sb[c];
  float ps[4], pd[4];
#pragma unroll
  for (int r = 0; r < 4; ++r) {
    int orow = orow0 + r;
    int er = (orow < E) ? orow : (E - 1);
    int s = ei[er], d = ei[E + er];
    ps[r] = PQ[(size_t)s * 32 + c];
    pd[r] = PQ[(size_t)d * 32 + 16 + c];
  }
#pragma unroll
  for (int r = 0; r < 4; ++r) {
    float l = acc[r] + bb + ps[r] + pd[r];
    float m = l;
#pragma unroll
    for (int w = 1; w < 16; w <<= 1) m = fmaxf(m, __shfl_xor(m, w));
    float ex = __expf(l - m);
    float sum = ex;
#pragma unroll
    for (int w = 1; w < 16; w <<= 1) sum += __shfl_xor(sum, w);
    float lse = __logf(sum) + m;
    int orow = orow0 + r;
    if (orow < E) out[(size_t)orow * NC + c] = l - lse;
  }
}

// ---------------- launch ----------------

extern "C" void kernel_launch(void* const* d_in, const int* in_sizes, int n_in,
                              void* d_out, int out_size, void* d_ws, size_t ws_size,
                              hipStream_t stream) {
  const float* x   = (const float*)d_in[0];
  const int*   ei  = (const int*)d_in[1];
  const float* ea  = (const float*)d_in[2];
  const float* W1  = (const float*)d_in[3];
  const float* b1  = (const float*)d_in[4];
  const float* W2  = (const float*)d_in[5];
  const float* b2  = (const float*)d_in[6];
  const float* W3  = (const float*)d_in[7];
  const float* b3  = (const float*)d_in[8];
  const float* Wfc = (const float*)d_in[9];
  const float* bfc = (const float*)d_in[10];
  float* out = (float*)d_out;
  int N = in_sizes[0] / D_IN;
  int E = in_sizes[1] / 2;

  char* w = (char*)d_ws;
  size_t off = 0;
  auto alloc = [&](size_t bytes) -> char* {
    char* p = w + off;
    off += (bytes + 255) & ~(size_t)255;
    return p;
  };
  __hip_bfloat16* A = (__hip_bfloat16*)alloc((size_t)N * HDIM * 2);  // 25.6 MB
  __hip_bfloat16* B = (__hip_bfloat16*)alloc((size_t)N * HDIM * 2);  // 25.6 MB
  float* PQ     = (float*)alloc((size_t)N * 32 * 4);                 // 12.8 MB
  int*   col    = (int*)alloc((size_t)E * 4 + 256);                  // +pad for batch reads
  int*   epos   = (int*)alloc((size_t)E * 4);
  int*   deg    = (int*)alloc((size_t)N * 4);
  float* dinv   = (float*)alloc((size_t)N * 4);
  int*   rowptr = (int*)alloc((size_t)N * 4);
  int*   bsum   = (int*)alloc(1024 * 4);
  int*   boff   = (int*)alloc(1024 * 4);
  short* wp1    = (short*)alloc(16384 * 2);
  short* wp2    = (short*)alloc(16384 * 2);
  short* wp3    = (short*)alloc(16384 * 2);
  short* wpc    = (short*)alloc(4096 * 2);
  short* wpe    = (short*)alloc(512 * 2);

  hipMemsetAsync(deg, 0, (size_t)N * 4, stream);

  int eb = (E + 255) / 256;
  int sb = (N + SCAN_CHUNK - 1) / SCAN_CHUNK;
  count_deg<<<eb, 256, 0, stream>>>(ei, deg, epos, E);
  scan_blocksums<<<sb, 256, 0, stream>>>(deg, bsum, N);
  scan_offsets<<<1, 256, 0, stream>>>(bsum, boff, sb);
  scan_write<<<sb, 256, 0, stream>>>(deg, boff, rowptr, dinv, N);
  fill_csr<<<eb, 256, 0, stream>>>(ei, rowptr, epos, col, E);
  repack_w128<<<64, 256, 0, stream>>>(W1, wp1);
  repack_w128<<<64, 256, 0, stream>>>(W2, wp2);
  repack_w128<<<64, 256, 0, stream>>>(W3, wp3);
  repack_wcp<<<16, 256, 0, stream>>>(Wfc, wpc);
  repack_wea<<<2, 256, 0, stream>>>(Wfc, wpe);

  int gb = (N + 63) / 64;
  int geb = (E + 63) / 64;
  gemm_l1<<<gb, 256, 0, stream>>>(x, wp1, A, dinv, N);
  agg_gemm<8, false, true ><<<gb, 512, 0, stream>>>(A, dinv, rowptr, deg, col, b1, wp2, B, dinv, N);
  agg_gemm<8, false, true ><<<gb, 512, 0, stream>>>(B, dinv, rowptr, deg, col, b2, wp3, A, dinv, N);
  agg_gemm<2, true,  false><<<gb, 512, 0, stream>>>(A, dinv, rowptr, deg, col, b3, wpc, PQ, nullptr, N);
  edge_fused<<<geb, 256, 0, stream>>>(ei, ea, wpe, bfc, PQ, out, E);
}